// Round 4
// baseline (137.837 us; speedup 1.0000x reference)
//
#include <hip/hip_runtime.h>

#define NTAGS 64
#define START_TAG 1
#define END_TAG 63
#define LN2F 0.69314718055994530942f

typedef float v2f __attribute__((ext_vector_type(2)));
typedef float v4f __attribute__((ext_vector_type(4)));

// cross-lane helpers (VALU DPP for xor1/xor2, ds_swizzle for xor4)
static __device__ __forceinline__ float dpp_xor1(float x) {
    return __int_as_float(__builtin_amdgcn_mov_dpp(__float_as_int(x), 0xB1, 0xF, 0xF, true));
}
static __device__ __forceinline__ float dpp_xor2(float x) {
    return __int_as_float(__builtin_amdgcn_mov_dpp(__float_as_int(x), 0x4E, 0xF, 0xF, true));
}
static __device__ __forceinline__ float swz_xor4(float x) {
    return __int_as_float(__builtin_amdgcn_ds_swizzle(__float_as_int(x), 0x101F));
}

// reduce-scatter over the h dimension (partners lane^1, lane^2, lane^4; same g).
// acc[oo] holds partials for tile-outputs (2oo, 2oo+1). Keep-rule: surviving
// output bit == h bit at each stage, so lane (g,h) ends with tile-out h, i.e.
// global index 8g+h == lane. Returns that fully-reduced value.
static __device__ __forceinline__ float reduce8(const v2f* acc, int h) {
    float s0, s1, s2, s3;
    {
        v2f d, t;
        d.x = dpp_xor1(acc[0].x); d.y = dpp_xor1(acc[0].y); t = acc[0] + d; s0 = (h & 1) ? t.y : t.x;
        d.x = dpp_xor1(acc[1].x); d.y = dpp_xor1(acc[1].y); t = acc[1] + d; s1 = (h & 1) ? t.y : t.x;
        d.x = dpp_xor1(acc[2].x); d.y = dpp_xor1(acc[2].y); t = acc[2] + d; s2 = (h & 1) ? t.y : t.x;
        d.x = dpp_xor1(acc[3].x); d.y = dpp_xor1(acc[3].y); t = acc[3] + d; s3 = (h & 1) ? t.y : t.x;
    }
    float t0 = s0 + dpp_xor2(s0), t1 = s1 + dpp_xor2(s1);
    float t2 = s2 + dpp_xor2(s2), t3 = s3 + dpp_xor2(s3);
    float ua = (h & 2) ? t1 : t0;
    float ub = (h & 2) ? t3 : t2;
    float w0 = ua + swz_xor4(ua);
    float w1 = ub + swz_xor4(ub);
    return (h & 4) ? w1 : w0;
}

// acc[oo] = sum_{in=0..7} pf[in][oo] * x[in], x = (xa, xb)
static __device__ __forceinline__ void matpart(const v2f (*pf)[4], v4f xa, v4f xb, v2f* acc) {
    float xs0 = xa.x, xs1 = xa.y, xs2 = xa.z, xs3 = xa.w;
    float xs4 = xb.x, xs5 = xb.y, xs6 = xb.z, xs7 = xb.w;
#pragma unroll
    for (int oo = 0; oo < 4; ++oo) acc[oo] = pf[0][oo] * (v2f){xs0, xs0};
#define STEPIN(K, XS)                                                           \
    _Pragma("unroll") for (int oo = 0; oo < 4; ++oo)                            \
        acc[oo] = __builtin_elementwise_fma(pf[K][oo], (v2f){XS, XS}, acc[oo]);
    STEPIN(1, xs1) STEPIN(2, xs2) STEPIN(3, xs3)
    STEPIN(4, xs4) STEPIN(5, xs5) STEPIN(6, xs6) STEPIN(7, xs7)
#undef STEPIN
}

// ---------------------------------------------------------------------------
// blocks [0,npair):        forward chains, batches (2q, 2q+1) in one wave
// blocks [npair,2*npair):  backward chains, batches (2q, 2q+1) in one wave
// blocks [2*npair,+B):     gold path score
// Forward:  p' = (p^T expT) .* E_t   (t = 0..H-1)
// Backward: w' = expT (E_t .* w)     (t = S-1..H),  w_init = exp(T[:,END])
// Linear domain, exact power-of-2 rescale every 8 steps.
// ---------------------------------------------------------------------------
__global__ __launch_bounds__(64) void crf_chains(const float* __restrict__ feats,
                                                 const float* __restrict__ mask,
                                                 const int* __restrict__ tags,
                                                 const float* __restrict__ trans,
                                                 float* __restrict__ zv,
                                                 float* __restrict__ wv,
                                                 float* __restrict__ gs,
                                                 int* __restrict__ ez,
                                                 int* __restrict__ ew,
                                                 int S, int H, int B) {
    const int lane = threadIdx.x;
    const int bid = (int)blockIdx.x;
    const int npair = (B + 1) >> 1;

    if (bid >= 2 * npair) {
        // ---- gold path score ----
        const int b = bid - 2 * npair;
        const float* fb = feats + (size_t)b * S * NTAGS;
        const float* mb = mask + (size_t)b * S;
        const int* tb = tags + (size_t)b * S;
        float acc = 0.f, msum = 0.f;
        for (int t = lane; t < S; t += 64) {
            int cur = tb[t];
            int prev = (t == 0) ? START_TAG : tb[t - 1];
            float m = mb[t];
            acc += (fb[t * NTAGS + cur] + trans[prev * NTAGS + cur]) * m;
            msum += m;
        }
#pragma unroll
        for (int sh = 32; sh >= 1; sh >>= 1) {
            acc += __shfl_xor(acc, sh);
            msum += __shfl_xor(msum, sh);
        }
        if (lane == 0) {
            int seq_end = (int)(msum + 0.5f) - 1;
            int last = (seq_end >= 0) ? tb[seq_end] : START_TAG;
            gs[b] = acc + trans[last * NTAGS + END_TAG];
        }
        return;
    }

    const int h = lane & 7, g = lane >> 3;
    const bool is_fwd = bid < npair;
    const int q = is_fwd ? bid : bid - npair;
    const int b0 = 2 * q;
    const int b1 = (2 * q + 1 < B) ? 2 * q + 1 : 2 * q;

    // 8x8 tile of exp(trans), packed for pk_fma.
    // fwd: coeff[in][out] = expT[8h+in][8g+out]  (reduce over source tag i)
    // bwd: coeff[in][out] = expT[8g+out][8h+in]  (reduce over source tag j)
    v2f pf[8][4];
    {
        const int rowbase = is_fwd ? 8 * h : 8 * g;
        const int colbase = is_fwd ? 8 * g : 8 * h;
        float tile[8][8];
#pragma unroll
        for (int r = 0; r < 8; ++r) {
            const float* rp = trans + (rowbase + r) * NTAGS + colbase;
            v4f c0 = *(const v4f*)rp;
            v4f c1 = *(const v4f*)(rp + 4);
            tile[r][0] = __expf(c0.x); tile[r][1] = __expf(c0.y);
            tile[r][2] = __expf(c0.z); tile[r][3] = __expf(c0.w);
            tile[r][4] = __expf(c1.x); tile[r][5] = __expf(c1.y);
            tile[r][6] = __expf(c1.z); tile[r][7] = __expf(c1.w);
        }
        if (is_fwd) {
#pragma unroll
            for (int in = 0; in < 8; ++in)
#pragma unroll
                for (int oo = 0; oo < 4; ++oo)
                    pf[in][oo] = (v2f){tile[in][2 * oo], tile[in][2 * oo + 1]};
        } else {
#pragma unroll
            for (int in = 0; in < 8; ++in)
#pragma unroll
                for (int oo = 0; oo < 4; ++oo)
                    pf[in][oo] = (v2f){tile[2 * oo][in], tile[2 * oo + 1][in]};
        }
    }

    __shared__ __align__(16) float pl[2][NTAGS];
    const float* f0 = feats + (size_t)b0 * S * NTAGS;
    const float* f1 = feats + (size_t)b1 * S * NTAGS;
    const float* m0 = mask + (size_t)b0 * S;
    const float* m1 = mask + (size_t)b1 * S;

    int e0 = 0, e1 = 0;
    float E0[8], E1[8], M0[8], M1[8];

    if (is_fwd) {
        float p0 = (lane == START_TAG) ? 1.0f : 0.0f, p1 = p0;
#pragma unroll
        for (int u = 0; u < 8; ++u) {
            E0[u] = __expf(f0[u * NTAGS + lane]);
            E1[u] = __expf(f1[u * NTAGS + lane]);
            M0[u] = m0[u]; M1[u] = m1[u];
        }
        for (int t0 = 0; t0 < H; t0 += 8) {
            float EN0[8], EN1[8], MN0[8], MN1[8];
            const bool more = (t0 + 8) < H;
            if (more) {
#pragma unroll
                for (int u = 0; u < 8; ++u) {
                    EN0[u] = f0[(size_t)(t0 + 8 + u) * NTAGS + lane];
                    EN1[u] = f1[(size_t)(t0 + 8 + u) * NTAGS + lane];
                    MN0[u] = m0[t0 + 8 + u]; MN1[u] = m1[t0 + 8 + u];
                }
            }
#pragma unroll
            for (int u = 0; u < 8; ++u) {
                pl[0][lane] = p0;
                pl[1][lane] = p1;
                v4f a0 = *(const v4f*)&pl[0][8 * h];
                v4f c0 = *(const v4f*)&pl[0][8 * h + 4];
                v4f a1 = *(const v4f*)&pl[1][8 * h];
                v4f c1 = *(const v4f*)&pl[1][8 * h + 4];
                v2f acc0[4], acc1[4];
                matpart(pf, a0, c0, acc0);
                matpart(pf, a1, c1, acc1);
                float y0 = reduce8(acc0, h);
                float y1 = reduce8(acc1, h);
                p0 = (M0[u] != 0.0f) ? y0 * E0[u] : p0;
                p1 = (M1[u] != 0.0f) ? y1 * E1[u] : p1;
            }
            float mx0 = p0, mx1 = p1;
#pragma unroll
            for (int sh = 1; sh <= 32; sh <<= 1) {
                mx0 = fmaxf(mx0, __shfl_xor(mx0, sh));
                mx1 = fmaxf(mx1, __shfl_xor(mx1, sh));
            }
            int ex0, ex1;
            (void)frexpf(mx0, &ex0);
            (void)frexpf(mx1, &ex1);
            p0 = ldexpf(p0, -ex0); e0 += ex0;
            p1 = ldexpf(p1, -ex1); e1 += ex1;
            if (more) {
#pragma unroll
                for (int u = 0; u < 8; ++u) {
                    E0[u] = __expf(EN0[u]); E1[u] = __expf(EN1[u]);
                    M0[u] = MN0[u]; M1[u] = MN1[u];
                }
            }
        }
        zv[(size_t)b0 * NTAGS + lane] = p0;
        if (b1 != b0) zv[(size_t)b1 * NTAGS + lane] = p1;
        if (lane == 0) { ez[b0] = e0; if (b1 != b0) ez[b1] = e1; }
    } else {
        const int NB = S - H;
        float w0 = __expf(trans[lane * NTAGS + END_TAG]);
        float w1 = w0;
#pragma unroll
        for (int u = 0; u < 8; ++u) {
            E0[u] = __expf(f0[(size_t)(S - 1 - u) * NTAGS + lane]);
            E1[u] = __expf(f1[(size_t)(S - 1 - u) * NTAGS + lane]);
            M0[u] = m0[S - 1 - u]; M1[u] = m1[S - 1 - u];
        }
        for (int t0 = 0; t0 < NB; t0 += 8) {
            float EN0[8], EN1[8], MN0[8], MN1[8];
            const bool more = (t0 + 8) < NB;
            if (more) {
#pragma unroll
                for (int u = 0; u < 8; ++u) {
                    EN0[u] = f0[(size_t)(S - 1 - (t0 + 8 + u)) * NTAGS + lane];
                    EN1[u] = f1[(size_t)(S - 1 - (t0 + 8 + u)) * NTAGS + lane];
                    MN0[u] = m0[S - 1 - (t0 + 8 + u)]; MN1[u] = m1[S - 1 - (t0 + 8 + u)];
                }
            }
#pragma unroll
            for (int u = 0; u < 8; ++u) {
                pl[0][lane] = w0 * E0[u];
                pl[1][lane] = w1 * E1[u];
                v4f a0 = *(const v4f*)&pl[0][8 * h];
                v4f c0 = *(const v4f*)&pl[0][8 * h + 4];
                v4f a1 = *(const v4f*)&pl[1][8 * h];
                v4f c1 = *(const v4f*)&pl[1][8 * h + 4];
                v2f acc0[4], acc1[4];
                matpart(pf, a0, c0, acc0);
                matpart(pf, a1, c1, acc1);
                float y0 = reduce8(acc0, h);
                float y1 = reduce8(acc1, h);
                w0 = (M0[u] != 0.0f) ? y0 : w0;
                w1 = (M1[u] != 0.0f) ? y1 : w1;
            }
            float mx0 = w0, mx1 = w1;
#pragma unroll
            for (int sh = 1; sh <= 32; sh <<= 1) {
                mx0 = fmaxf(mx0, __shfl_xor(mx0, sh));
                mx1 = fmaxf(mx1, __shfl_xor(mx1, sh));
            }
            int ex0, ex1;
            (void)frexpf(mx0, &ex0);
            (void)frexpf(mx1, &ex1);
            w0 = ldexpf(w0, -ex0); e0 += ex0;
            w1 = ldexpf(w1, -ex1); e1 += ex1;
            if (more) {
#pragma unroll
                for (int u = 0; u < 8; ++u) {
                    E0[u] = __expf(EN0[u]); E1[u] = __expf(EN1[u]);
                    M0[u] = MN0[u]; M1[u] = MN1[u];
                }
            }
        }
        wv[(size_t)b0 * NTAGS + lane] = w0;
        if (b1 != b0) wv[(size_t)b1 * NTAGS + lane] = w1;
        if (lane == 0) { ew[b0] = e0; if (b1 != b0) ew[b1] = e1; }
    }
}

// ---------------------------------------------------------------------------
// combine + mean: out = mean_b( log(z_b . w_b) + (ez+ew)*ln2 - gs_b )
// ---------------------------------------------------------------------------
__global__ __launch_bounds__(1024) void crf_combine(const float* __restrict__ zv,
                                                    const float* __restrict__ wv,
                                                    const float* __restrict__ gs,
                                                    const int* __restrict__ ez,
                                                    const int* __restrict__ ew,
                                                    float* __restrict__ out, int B) {
    const int tid = threadIdx.x;
    const int wave = tid >> 6, lane = tid & 63;
    float local = 0.f;
    for (int b = wave; b < B; b += 16) {
        float s = zv[(size_t)b * NTAGS + lane] * wv[(size_t)b * NTAGS + lane];
#pragma unroll
        for (int sh = 32; sh >= 1; sh >>= 1) s += __shfl_xor(s, sh);
        if (lane == 0)
            local += logf(s) + (float)(ez[b] + ew[b]) * LN2F - gs[b];
    }
    __shared__ float buf[16];
    if (lane == 0) buf[wave] = local;
    __syncthreads();
    if (tid == 0) {
        float a = 0.f;
#pragma unroll
        for (int i = 0; i < 16; ++i) a += buf[i];
        out[0] = a / (float)B;
    }
}

extern "C" void kernel_launch(void* const* d_in, const int* in_sizes, int n_in,
                              void* d_out, int out_size, void* d_ws, size_t ws_size,
                              hipStream_t stream) {
    const float* feats = (const float*)d_in[0];
    const float* mask  = (const float*)d_in[1];
    const int*   tags  = (const int*)d_in[2];
    const float* trans = (const float*)d_in[3];
    float* out = (float*)d_out;

    const int S = 512;              // reference shape
    const int B = in_sizes[1] / S;  // mask is (B,S)
    const int H = S / 2;
    const int npair = (B + 1) >> 1;

    float* zv = (float*)d_ws;
    float* wv = zv + (size_t)B * NTAGS;
    float* gs = wv + (size_t)B * NTAGS;
    int* ez = (int*)(gs + B);
    int* ew = ez + B;

    crf_chains<<<2 * npair + B, 64, 0, stream>>>(feats, mask, tags, trans,
                                                 zv, wv, gs, ez, ew, S, H, B);
    crf_combine<<<1, 1024, 0, stream>>>(zv, wv, gs, ez, ew, out, B);
}